// Round 19
// baseline (481.136 us; speedup 1.0000x reference)
//
#include <hip/hip_runtime.h>

#define E_EDGES 131072
#define FIN 16
#define FF 32

// ---- combo tables: 11 allowed (l1,l2,l3); blocks l=0:[0,1) l=1:[1,4) l=2:[4,9) ----
constexpr int CIDX[11] = {0, 4, 8, 10, 12, 14, 16, 20, 22, 24, 26};
constexpr int CA0[11] = {0, 0, 0, 1, 1, 1, 1, 4, 4, 4, 4};
constexpr int CDA[11] = {1, 1, 1, 3, 3, 3, 3, 5, 5, 5, 5};
constexpr int CQ0[11] = {0, 1, 4, 0, 1, 1, 4, 0, 1, 4, 4};
constexpr int CC0[11] = {0, 1, 4, 1, 0, 4, 1, 4, 1, 0, 4};
constexpr int CDC[11] = {1, 3, 5, 3, 1, 5, 3, 5, 3, 1, 5};
constexpr int CL2[11] = {0, 1, 2, 0, 1, 1, 2, 0, 1, 2, 2};
constexpr int CZ0[11] = {0, 1, 4, 9, 18, 21, 36, 45, 70, 85, 90};    // unpadded cum, 115
constexpr int CZP[11] = {0, 4, 8, 16, 28, 32, 48, 60, 88, 104, 112}; // pad4 offsets, 140

#define TBL_N 512
#define TBL_RMAX 12.0
#define TBL_INVH ((float)(511.0 / 12.0))

struct P8 { float* p[8]; };

// ---------------- Gaunt tensor via exact quadrature (matches reference) -------------
__global__ void gaunt_init(float* __restrict__ G) {
    __shared__ double Ys[128][9];
    __shared__ double wq[128];
    const double ct[8] = {
        -0.9602898564975363, -0.7966664774136267, -0.5255324099163290, -0.1834346424956498,
         0.1834346424956498,  0.5255324099163290,  0.7966664774136267,  0.9602898564975363};
    const double wgt[8] = {
        0.1012285362903763, 0.2223810344533745, 0.3137066458778873, 0.3626837833783620,
        0.3626837833783620, 0.3137066458778873, 0.2223810344533745, 0.1012285362903763};
    const double PI = 3.141592653589793238462643383279502884;
    int t = threadIdx.x;
    if (t < 128) {
        int iq = t >> 4, ip = t & 15;
        double c = ct[iq];
        double s = sqrt(1.0 - c * c);
        double phi = (double)ip * (2.0 * PI / 16.0);
        double x = s * cos(phi), y = s * sin(phi), z = c;
        double* Yp = Ys[t];
        Yp[0] = 0.28209479177387814;
        Yp[1] = 0.4886025119029199 * y;
        Yp[2] = 0.4886025119029199 * z;
        Yp[3] = 0.4886025119029199 * x;
        Yp[4] = 1.0925484305920792 * x * y;
        Yp[5] = 1.0925484305920792 * y * z;
        Yp[6] = 0.31539156525252005 * (3.0 * z * z - 1.0);
        Yp[7] = 1.0925484305920792 * x * z;
        Yp[8] = 0.5462742152960396 * (x * x - y * y);
        wq[t] = wgt[iq] * (2.0 * PI / 16.0);
    }
    __syncthreads();
    for (int idx = t; idx < 729; idx += blockDim.x) {
        int a = idx / 81, b = (idx / 9) % 9, cc = idx % 9;
        double sum = 0.0;
        for (int q = 0; q < 128; ++q) sum += wq[q] * Ys[q][a] * Ys[q][b] * Ys[q][cc];
        G[idx] = (float)sum;
    }
}

// ---------------- small utility kernels ---------------------------------------------
__global__ __launch_bounds__(256) void zero_kernel(float* __restrict__ p, size_t n) {
    size_t i = (size_t)blockIdx.x * 256 + threadIdx.x;
    if (i < n) p[i] = 0.f;
}
__global__ __launch_bounds__(256) void fill_int(int* __restrict__ p, int n, int v) {
    int i = blockIdx.x * 256 + threadIdx.x;
    if (i < n) p[i] = v;
}

// ---------------- CSR build ----------------------------------------------------------
__global__ __launch_bounds__(256) void csr_count(const int* __restrict__ dst,
                                                 int* __restrict__ cnt) {
    int e = blockIdx.x * 256 + threadIdx.x;
    atomicAdd(&cnt[dst[e]], 1);  // 131072 spread addresses: low contention
}
__global__ __launch_bounds__(256) void csr_bsum(const int* __restrict__ cnt,
                                                int* __restrict__ bsum) {
    int i = blockIdx.x * 256 + threadIdx.x;
    int v = cnt[i];
#pragma unroll
    for (int off = 32; off; off >>= 1) v += __shfl_down(v, off, 64);
    __shared__ int w4[4];
    if ((threadIdx.x & 63) == 0) w4[threadIdx.x >> 6] = v;
    __syncthreads();
    if (threadIdx.x == 0) bsum[blockIdx.x] = w4[0] + w4[1] + w4[2] + w4[3];
}
__global__ void scan512_wave(int* __restrict__ b) {
    int lane = threadIdx.x;  // 64 threads
    int run = 0;
    for (int c = 0; c < 8; ++c) {
        int v = b[c * 64 + lane];
        int s = v;
#pragma unroll
        for (int off = 1; off < 64; off <<= 1) {
            int t = __shfl_up(s, off, 64);
            if (lane >= off) s += t;
        }
        b[c * 64 + lane] = run + s - v;
        run += __shfl(s, 63, 64);
    }
}
__global__ __launch_bounds__(256) void csr_row(const int* __restrict__ cnt,
                                               const int* __restrict__ bsum,
                                               int* __restrict__ row_start,
                                               int* __restrict__ cursor) {
    __shared__ int sd[256];
    const int i = blockIdx.x * 256 + threadIdx.x;
    const int my = cnt[i];
    sd[threadIdx.x] = my;
    __syncthreads();
    for (int off = 1; off < 256; off <<= 1) {
        int t = (threadIdx.x >= off) ? sd[threadIdx.x - off] : 0;
        __syncthreads();
        sd[threadIdx.x] += t;
        __syncthreads();
    }
    int rs = bsum[blockIdx.x] + sd[threadIdx.x] - my;
    row_start[i] = rs;
    cursor[i] = rs;
    if (blockIdx.x == 511 && threadIdx.x == 255)
        row_start[E_EDGES] = bsum[511] + sd[255];
}
__global__ __launch_bounds__(256) void csr_scatter(const int* __restrict__ dst,
                                                   int* __restrict__ cursor,
                                                   int* __restrict__ eidx) {
    int e = blockIdx.x * 256 + threadIdx.x;
    int pos = atomicAdd(&cursor[dst[e]], 1);  // spread addresses: fine
    eidx[pos] = e;
}

// ---------------- degree counting-sort, DESCENDING degree (LPT schedule) ------------
__global__ __launch_bounds__(256) void sort1(const int* __restrict__ cnt,
                                             int* __restrict__ blockhist) {
    __shared__ int h[32];
    if (threadIdx.x < 32) h[threadIdx.x] = 0;
    __syncthreads();
    int n = blockIdx.x * 256 + threadIdx.x;
    int d = cnt[n]; if (d > 31) d = 31;
    atomicAdd(&h[31 - d], 1);  // bin flip: heavy nodes first
    __syncthreads();
    if (threadIdx.x < 32) blockhist[threadIdx.x * 512 + blockIdx.x] = h[threadIdx.x];
}
__global__ __launch_bounds__(1024) void sort2(int* __restrict__ blockhist) {
    __shared__ int tot[32];
    int wv = threadIdx.x >> 6, lane = threadIdx.x & 63;  // 16 waves, 2 bins each
#pragma unroll
    for (int bi = 0; bi < 2; ++bi) {
        int bin = wv * 2 + bi;
        int run = 0;
        for (int c = 0; c < 8; ++c) {
            int v = blockhist[bin * 512 + c * 64 + lane];
            int s = v;
#pragma unroll
            for (int off = 1; off < 64; off <<= 1) {
                int t = __shfl_up(s, off, 64);
                if (lane >= off) s += t;
            }
            blockhist[bin * 512 + c * 64 + lane] = run + s - v;
            run += __shfl(s, 63, 64);
        }
        if (lane == 0) tot[bin] = run;
    }
    __syncthreads();
    if (threadIdx.x == 0) {
        int run = 0;
        for (int i = 0; i < 32; ++i) { int t = tot[i]; tot[i] = run; run += t; }
    }
    __syncthreads();
#pragma unroll
    for (int bi = 0; bi < 2; ++bi) {
        int bin = wv * 2 + bi;
        int base = tot[bin];
        for (int c = 0; c < 8; ++c) blockhist[bin * 512 + c * 64 + lane] += base;
    }
}
__global__ __launch_bounds__(256) void sort3(const int* __restrict__ cnt,
                                             const int* __restrict__ blockhist,
                                             int* __restrict__ perm) {
    __shared__ int cur[32];
    if (threadIdx.x < 32) cur[threadIdx.x] = blockhist[threadIdx.x * 512 + blockIdx.x];
    __syncthreads();
    int n = blockIdx.x * 256 + threadIdx.x;
    int d = cnt[n]; if (d > 31) d = 31;
    int pos = atomicAdd(&cur[31 - d], 1);  // bin flip (must match sort1)
    perm[pos] = n;
}

// ---------------- geometry packet, CSR order: {rx, ry, rz, bits(src)} ---------------
__global__ __launch_bounds__(256) void geo_prep(const float* __restrict__ coords,
                                                const int* __restrict__ dst,
                                                const int* __restrict__ src,
                                                const int* __restrict__ eidx,
                                                float4* __restrict__ geo) {
    int p = blockIdx.x * 256 + threadIdx.x;
    int e = eidx[p];
    int s = src[e], d = dst[e];
    float4 g;
    g.x = coords[3 * d + 0] - coords[3 * s + 0];
    g.y = coords[3 * d + 1] - coords[3 * s + 1];
    g.z = coords[3 * d + 2] - coords[3 * s + 2];
    g.w = __int_as_float(s);
    geo[p] = g;
}

// ---------------- coef lookup table, layout [u][f][12] (k padded 11->12) ------------
__global__ __launch_bounds__(256) void build_tbl12(const float* __restrict__ Wm,
                                                   const float* __restrict__ bm,
                                                   float* __restrict__ tbl) {
    __shared__ float rad[32];
    const int u = blockIdx.x;
    const int tid = threadIdx.x;
    if (tid < 32) {
        double r = (double)u * (TBL_RMAX / (double)(TBL_N - 1));
        double c = (double)tid * (4.0 / 31.0);
        double d = r - c;
        rad[tid] = (float)exp(-d * d);
    }
    __syncthreads();
    for (int i = tid; i < 352; i += 256) {
        int k = i >> 5, f = i & 31;
        float acc = bm[CIDX[k] * 32 + f];
        const float* W = Wm + CIDX[k] * 1024 + f;
#pragma unroll
        for (int b = 0; b < 32; ++b) acc = fmaf(rad[b], W[b * 32], acc);
        tbl[(size_t)u * 384 + f * 12 + k] = acc;
    }
}

// ---------------- embed6: coop LDS stage of x + W0 in regs + float4 out -------------
template <int CW>
__global__ __launch_bounds__(256) void embed6(
    const float* __restrict__ xin, const float* __restrict__ W0,
    const float* __restrict__ b0, P8 P) {
    constexpr int K = 32 / CW;
    __shared__ float4 Xin4[288];   // 8 edges x 36 float4 (4608 B), coalesced-staged
    __shared__ float Xs[8][9][36];
    const int tid = threadIdx.x;
    const int g = tid >> 5, f = tid & 31;
    float w0r[3][16];
#pragma unroll
    for (int l = 0; l < 3; ++l)
#pragma unroll
        for (int gi = 0; gi < 16; ++gi) w0r[l][gi] = W0[(l * FIN + gi) * FF + f];
    const float b0f = b0[f];

    constexpr int NG = E_EDGES / 8;  // 16384 edge-groups
    for (int nb = blockIdx.x; nb < NG; nb += gridDim.x) {
        const size_t e0 = (size_t)nb * 8;
        const float4* src4 = (const float4*)(xin + e0 * 144);
        for (int i = tid; i < 288; i += 256) Xin4[i] = src4[i];
        __syncthreads();  // bar A (also protects prior iter's Xs copy-out reads)
#pragma unroll
        for (int c = 0; c < 9; ++c) {
            const int l = (c == 0) ? 0 : ((c < 4) ? 1 : 2);
            float acc = (c == 0) ? b0f : 0.f;
#pragma unroll
            for (int q = 0; q < 4; ++q) {
                float4 xv = Xin4[g * 36 + c * 4 + q];
                acc = fmaf(xv.x, w0r[l][q * 4 + 0], acc);
                acc = fmaf(xv.y, w0r[l][q * 4 + 1], acc);
                acc = fmaf(xv.z, w0r[l][q * 4 + 2], acc);
                acc = fmaf(xv.w, w0r[l][q * 4 + 3], acc);
            }
            Xs[g][c][f] = acc;
        }
        __syncthreads();  // bar B
        constexpr int QW = CW / 4;
        constexpr int RSZ4 = 8 * 9 * QW;
#pragma unroll
        for (int h = 0; h < K; ++h) {
            float4* dstp = (float4*)(P.p[h] + e0 * 9 * CW);
            for (int i = tid; i < RSZ4; i += 256) {
                int fq = i % QW;
                int rc = i / QW;
                float4 v = *(const float4*)&Xs[rc / 9][rc % 9][h * CW + fq * 4];
                dstp[i] = v;
            }
        }
    }
}

// ---------------- per-combo einsum piece (all compile-time indexed) -----------------
template <int K>
__device__ __forceinline__ void comboP(const float* __restrict__ zrow,
                                       const float (&coef)[11], const float (&xa)[9],
                                       float (&acc)[9]) {
    constexpr int A0 = CA0[K], DA = CDA[K], C0 = CC0[K], DC = CDC[K];
    constexpr int SZ = DA * DC, N4 = (SZ + 3) / 4, ZP = CZP[K];
    float zz[N4 * 4];
    const float4* zp = (const float4*)(zrow + ZP);
#pragma unroll
    for (int j = 0; j < N4; ++j) {
        float4 v = zp[j];
        zz[4 * j + 0] = v.x; zz[4 * j + 1] = v.y; zz[4 * j + 2] = v.z; zz[4 * j + 3] = v.w;
    }
    float m[DC] = {};
#pragma unroll
    for (int a = 0; a < DA; ++a)
#pragma unroll
        for (int c = 0; c < DC; ++c) m[c] = fmaf(xa[A0 + a], zz[a * DC + c], m[c]);
#pragma unroll
    for (int c = 0; c < DC; ++c) acc[C0 + c] = fmaf(coef[K], m[c], acc[C0 + c]);
}

// ---------------- message pass, CSR pull, chunk h, CUBIC tbl, utab in regs ----------
template <int CW, bool GEO>
__global__ __launch_bounds__(256) void mp_pull5(
    const float* __restrict__ Xold, float* __restrict__ Xnew,
    const float* __restrict__ coords,
    const int* __restrict__ row_start, const int* __restrict__ eidx,
    const int* __restrict__ src, const int* __restrict__ perm,
    const float4* __restrict__ geo,
    const float* __restrict__ tbl, const float* __restrict__ Gglob, int h) {
    constexpr int EPB = 256 / CW;
    constexpr int NB_TOT = E_EDGES / EPB;
    constexpr int NJ = (115 + CW - 1) / CW;  // z entries per lane
    __shared__ float gG[729];
    __shared__ float z_s[EPB * 140];
    const int tid = threadIdx.x;
    for (int i = tid; i < 729; i += 256) gG[i] = Gglob[i];
    __syncthreads();

    const int g = tid / CW, fc = tid % CW;
    const int f = h * CW + fc;
    float* zrow = &z_s[g * 140];

    // per-lane z-table entries (STATIC index -> registers, computed once)
    int utab[NJ];
#pragma unroll
    for (int j = 0; j < NJ; ++j) {
        int t = fc + j * CW;
        int enc = 0;
        if (t < 115) {
            int k = 0;
#pragma unroll
            for (int kk = 1; kk < 11; ++kk) if (t >= CZ0[kk]) k = kk;
            int loc = t - CZ0[k];
            int dc = CDC[k];
            int a = loc / dc, c = loc - a * dc;
            int base = (CA0[k] + a) * 81 + CQ0[k] * 9 + (CC0[k] + c);
            enc = ((CZP[k] + loc) << 12) | (CL2[k] << 10) | base;
        }
        utab[j] = enc;
    }

    for (int nb = blockIdx.x; nb < NB_TOT; nb += gridDim.x) {
        const int d = perm[nb * EPB + g];
        const int r0 = row_start[d], r1 = row_start[d + 1];
        float acc[9];
#pragma unroll
        for (int a = 0; a < 9; ++a) acc[a] = Xold[((size_t)d * 9 + a) * CW + fc];
        float ddx = 0.f, ddy = 0.f, ddz = 0.f;
        if (!GEO) { ddx = coords[3 * d]; ddy = coords[3 * d + 1]; ddz = coords[3 * d + 2]; }

        // 1-deep software pipeline over the row's edges
        float prx = 0.f, pry = 0.f, prz = 0.f;
        int ps = 0;
        float pxa[9];
        if (r0 < r1) {
            if (GEO) {
                float4 gv = geo[r0];
                prx = gv.x; pry = gv.y; prz = gv.z; ps = __float_as_int(gv.w);
            } else {
                int pe = eidx[r0]; ps = src[pe];
                prx = ddx - coords[3 * ps]; pry = ddy - coords[3 * ps + 1];
                prz = ddz - coords[3 * ps + 2];
            }
#pragma unroll
            for (int a = 0; a < 9; ++a) pxa[a] = Xold[((size_t)ps * 9 + a) * CW + fc];
        }
        for (int p = r0; p < r1; ++p) {
            const float rx = prx, ry = pry, rz = prz;
            float xa[9];
#pragma unroll
            for (int a = 0; a < 9; ++a) xa[a] = pxa[a];
            if (p + 1 < r1) {  // prefetch next edge under this edge's compute
                if (GEO) {
                    float4 gv = geo[p + 1];
                    prx = gv.x; pry = gv.y; prz = gv.z; ps = __float_as_int(gv.w);
                } else {
                    int pe = eidx[p + 1]; ps = src[pe];
                    prx = ddx - coords[3 * ps]; pry = ddy - coords[3 * ps + 1];
                    prz = ddz - coords[3 * ps + 2];
                }
#pragma unroll
                for (int a = 0; a < 9; ++a) pxa[a] = Xold[((size_t)ps * 9 + a) * CW + fc];
            }
            float r = sqrtf(rx * rx + ry * ry + rz * rz + 1e-8f);
            float inv = 1.f / r;
            float ux = rx * inv, uy = ry * inv, uz = rz * inv;
            float y9[9];
            y9[0] = 0.28209479177387814f;
            y9[1] = 0.4886025119029199f * uy; y9[2] = 0.4886025119029199f * uz;
            y9[3] = 0.4886025119029199f * ux;
            y9[4] = 1.0925484305920792f * ux * uy; y9[5] = 1.0925484305920792f * uy * uz;
            y9[6] = 0.31539156525252005f * (3.f * uz * uz - 1.f);
            y9[7] = 1.0925484305920792f * ux * uz;
            y9[8] = 0.5462742152960396f * (ux * ux - uy * uy);
            // coef via CUBIC Lagrange interp; tbl layout [u][f][12]
            float rt = r * TBL_INVH;
            int u = (int)rt;
            u = (u < 1) ? 1 : ((u > TBL_N - 3) ? (TBL_N - 3) : u);
            float w = rt - (float)u;
            float wp1 = w + 1.f, wm1 = w - 1.f, wm2 = w - 2.f;
            float lm = -w * wm1 * wm2 * (1.f / 6.f);
            float l0 = wp1 * wm1 * wm2 * 0.5f;
            float l1 = -wp1 * w * wm2 * 0.5f;
            float l2 = wp1 * w * wm1 * (1.f / 6.f);
            const float* tbp = tbl + (size_t)(u - 1) * 384 + f * 12;
            float coef[11];
            {
                float4 a0 = *(const float4*)(tbp);
                float4 a1 = *(const float4*)(tbp + 4);
                float4 a2 = *(const float4*)(tbp + 8);
                float tk[12] = {a0.x, a0.y, a0.z, a0.w, a1.x, a1.y, a1.z, a1.w,
                                a2.x, a2.y, a2.z, a2.w};
#pragma unroll
                for (int k = 0; k < 11; ++k) coef[k] = lm * tk[k];
            }
#pragma unroll
            for (int tap = 0; tap < 3; ++tap) {
                const float lw = (tap == 0) ? l0 : ((tap == 1) ? l1 : l2);
                const float* tq = tbp + (tap + 1) * 384;
                float4 a0 = *(const float4*)(tq);
                float4 a1 = *(const float4*)(tq + 4);
                float4 a2 = *(const float4*)(tq + 8);
                float tk[12] = {a0.x, a0.y, a0.z, a0.w, a1.x, a1.y, a1.z, a1.w,
                                a2.x, a2.y, a2.z, a2.w};
#pragma unroll
                for (int k = 0; k < 11; ++k) coef[k] = fmaf(lw, tk[k], coef[k]);
            }
            // z[t] = sum_b Y[Q0+b] * G[base + 9b]; utab from registers, gG broadcast
#pragma unroll
            for (int j = 0; j < NJ; ++j) {
                int t = fc + j * CW;
                if (t < 115) {
                    int u2 = utab[j];
                    int base = u2 & 0x3FF;
                    int l2u = (u2 >> 10) & 3;
                    float zv;
                    if (l2u == 0) {
                        zv = y9[0] * gG[base];
                    } else if (l2u == 1) {
                        zv = y9[1] * gG[base];
                        zv = fmaf(y9[2], gG[base + 9], zv);
                        zv = fmaf(y9[3], gG[base + 18], zv);
                    } else {
                        zv = y9[4] * gG[base];
                        zv = fmaf(y9[5], gG[base + 9], zv);
                        zv = fmaf(y9[6], gG[base + 18], zv);
                        zv = fmaf(y9[7], gG[base + 27], zv);
                        zv = fmaf(y9[8], gG[base + 36], zv);
                    }
                    zrow[u2 >> 12] = zv;
                }
            }
            asm volatile("s_waitcnt lgkmcnt(0)" ::: "memory");
            comboP<0>(zrow, coef, xa, acc);
            comboP<1>(zrow, coef, xa, acc);
            comboP<2>(zrow, coef, xa, acc);
            comboP<3>(zrow, coef, xa, acc);
            comboP<4>(zrow, coef, xa, acc);
            comboP<5>(zrow, coef, xa, acc);
            comboP<6>(zrow, coef, xa, acc);
            comboP<7>(zrow, coef, xa, acc);
            comboP<8>(zrow, coef, xa, acc);
            comboP<9>(zrow, coef, xa, acc);
            comboP<10>(zrow, coef, xa, acc);
        }
#pragma unroll
        for (int a = 0; a < 9; ++a) Xnew[((size_t)d * 9 + a) * CW + fc] = acc[a];
    }
}

// ---------------- DPP helpers --------------------------------------------------------
template <int CTRL>
__device__ __forceinline__ float dpp_add(float v) {
    int t = __builtin_amdgcn_update_dpp(0, __builtin_bit_cast(int, v),
                                        CTRL, 0xF, 0xF, true);
    return v + __builtin_bit_cast(float, t);
}
__device__ __forceinline__ float red8(float v) {
    v = dpp_add<0x111>(v);  // row_shr:1
    v = dpp_add<0x112>(v);  // row_shr:2
    v = dpp_add<0x114>(v);  // row_shr:4
    return v;               // valid in lane 7 of each 8-lane group
}

// ---------------- final10: 16 edges/wave (pairs), W quad amortized over 2 edges -----
template <int CW>
__global__ __launch_bounds__(256) void final10(
    P8 P, const float* __restrict__ W1, const float* __restrict__ b1,
    const float* __restrict__ W2, const float* __restrict__ b2,
    float* __restrict__ out) {
    constexpr int K = 32 / CW;
    constexpr int QPR = CW / 4;  // f-quads per region
    __shared__ float W_s[3 * 32 * 32];  // 12 KB, same layout as W1
    const int tid = threadIdx.x;
    for (int i = tid; i < 3072; i += 256) W_s[i] = W1[i];
    __syncthreads();

    const int lane = tid & 63;
    const int e_sub = lane >> 3;   // 8 edge-slots per wave
    const int fq = lane & 7;       // 8 f-quads, this lane owns f = fq*4 .. fq*4+3
    float w2r[3][4];
#pragma unroll
    for (int l = 0; l < 3; ++l)
#pragma unroll
        for (int j = 0; j < 4; ++j) w2r[l][j] = W2[l * 32 + fq * 4 + j];
    float b1r[4];
#pragma unroll
    for (int j = 0; j < 4; ++j) b1r[j] = b1[fq * 4 + j];
    const float b20 = b2[0];

    const int wv = (blockIdx.x * 256 + tid) >> 6;
    const int nw = (gridDim.x * 256) >> 6;
    constexpr int NG2 = E_EDGES / 16;  // 8192 pair-groups

    for (int gp = wv; gp < NG2; gp += nw) {
        const size_t eA = (size_t)gp * 16 + e_sub;  // edge A
        const size_t eB = eA + 8;                   // edge B
        float tA[9][4], tB[9][4];
#pragma unroll
        for (int j = 0; j < 4; ++j) { tA[0][j] = b1r[j]; tB[0][j] = b1r[j]; }
#pragma unroll
        for (int c = 1; c < 9; ++c)
#pragma unroll
            for (int j = 0; j < 4; ++j) { tA[c][j] = 0.f; tB[c][j] = 0.f; }

#pragma unroll 1
        for (int h = 0; h < K; ++h) {          // region loop: NOT unrolled
            const float* rb = P.p[0];
#pragma unroll
            for (int i = 1; i < K; ++i) rb = (h == i) ? P.p[i] : rb;
            const float* xbA = rb + (eA * 9) * CW;
            const float* xbB = rb + (eB * 9) * CW;
#pragma unroll 1
            for (int q2 = 0; q2 < QPR; ++q2) { // quad-in-region loop: NOT unrolled
                const int gq = h * QPR + q2;
                const float* xA = xbA + q2 * 4;
                const float* xB = xbB + q2 * 4;
                float wq[4][4];  // W quad for ONE l-class, reused by BOTH edges
                // ---- l = 0 : c = 0 ----
#pragma unroll
                for (int gi = 0; gi < 4; ++gi) {
                    float4 wv4 = *(const float4*)&W_s[(0 * 32 + gq * 4 + gi) * 32 + fq * 4];
                    wq[gi][0] = wv4.x; wq[gi][1] = wv4.y; wq[gi][2] = wv4.z; wq[gi][3] = wv4.w;
                }
                {
                    float4 xv = *(const float4*)&xA[0 * CW];
                    float xr[4] = {xv.x, xv.y, xv.z, xv.w};
#pragma unroll
                    for (int gi = 0; gi < 4; ++gi)
#pragma unroll
                        for (int j = 0; j < 4; ++j) tA[0][j] = fmaf(xr[gi], wq[gi][j], tA[0][j]);
                    float4 yv = *(const float4*)&xB[0 * CW];
                    float yr[4] = {yv.x, yv.y, yv.z, yv.w};
#pragma unroll
                    for (int gi = 0; gi < 4; ++gi)
#pragma unroll
                        for (int j = 0; j < 4; ++j) tB[0][j] = fmaf(yr[gi], wq[gi][j], tB[0][j]);
                }
                __builtin_amdgcn_sched_barrier(0);
                // ---- l = 1 : c = 1..3 ----
#pragma unroll
                for (int gi = 0; gi < 4; ++gi) {
                    float4 wv4 = *(const float4*)&W_s[(1 * 32 + gq * 4 + gi) * 32 + fq * 4];
                    wq[gi][0] = wv4.x; wq[gi][1] = wv4.y; wq[gi][2] = wv4.z; wq[gi][3] = wv4.w;
                }
#pragma unroll
                for (int c = 1; c < 4; ++c) {
                    float4 xv = *(const float4*)&xA[c * CW];
                    float xr[4] = {xv.x, xv.y, xv.z, xv.w};
#pragma unroll
                    for (int gi = 0; gi < 4; ++gi)
#pragma unroll
                        for (int j = 0; j < 4; ++j) tA[c][j] = fmaf(xr[gi], wq[gi][j], tA[c][j]);
                    float4 yv = *(const float4*)&xB[c * CW];
                    float yr[4] = {yv.x, yv.y, yv.z, yv.w};
#pragma unroll
                    for (int gi = 0; gi < 4; ++gi)
#pragma unroll
                        for (int j = 0; j < 4; ++j) tB[c][j] = fmaf(yr[gi], wq[gi][j], tB[c][j]);
                }
                __builtin_amdgcn_sched_barrier(0);
                // ---- l = 2 : c = 4..8 ----
#pragma unroll
                for (int gi = 0; gi < 4; ++gi) {
                    float4 wv4 = *(const float4*)&W_s[(2 * 32 + gq * 4 + gi) * 32 + fq * 4];
                    wq[gi][0] = wv4.x; wq[gi][1] = wv4.y; wq[gi][2] = wv4.z; wq[gi][3] = wv4.w;
                }
#pragma unroll
                for (int c = 4; c < 9; ++c) {
                    float4 xv = *(const float4*)&xA[c * CW];
                    float xr[4] = {xv.x, xv.y, xv.z, xv.w};
#pragma unroll
                    for (int gi = 0; gi < 4; ++gi)
#pragma unroll
                        for (int j = 0; j < 4; ++j) tA[c][j] = fmaf(xr[gi], wq[gi][j], tA[c][j]);
                    float4 yv = *(const float4*)&xB[c * CW];
                    float yr[4] = {yv.x, yv.y, yv.z, yv.w};
#pragma unroll
                    for (int gi = 0; gi < 4; ++gi)
#pragma unroll
                        for (int j = 0; j < 4; ++j) tB[c][j] = fmaf(yr[gi], wq[gi][j], tB[c][j]);
                }
                __builtin_amdgcn_sched_barrier(0);
            }
        }
        // ---- epilogue edge A ----
        {
            float gw[3][4];
#pragma unroll
            for (int j = 0; j < 4; ++j) {
                const float gate = (tA[0][j] > 0.f) ? 1.f : 0.f;
#pragma unroll
                for (int l = 0; l < 3; ++l) gw[l][j] = gate * w2r[l][j];
            }
#pragma unroll
            for (int c = 0; c < 9; ++c) {
                const int l = (c == 0) ? 0 : ((c < 4) ? 1 : 2);
                float v = tA[c][0] * gw[l][0];
                v = fmaf(tA[c][1], gw[l][1], v);
                v = fmaf(tA[c][2], gw[l][2], v);
                v = fmaf(tA[c][3], gw[l][3], v);
                v = red8(v);
                if (fq == 7) out[eA * 9 + c] = v + ((c == 0) ? b20 : 0.f);
            }
        }
        // ---- epilogue edge B ----
        {
            float gw[3][4];
#pragma unroll
            for (int j = 0; j < 4; ++j) {
                const float gate = (tB[0][j] > 0.f) ? 1.f : 0.f;
#pragma unroll
                for (int l = 0; l < 3; ++l) gw[l][j] = gate * w2r[l][j];
            }
#pragma unroll
            for (int c = 0; c < 9; ++c) {
                const int l = (c == 0) ? 0 : ((c < 4) ? 1 : 2);
                float v = tB[c][0] * gw[l][0];
                v = fmaf(tB[c][1], gw[l][1], v);
                v = fmaf(tB[c][2], gw[l][2], v);
                v = fmaf(tB[c][3], gw[l][3], v);
                v = red8(v);
                if (fq == 7) out[eB * 9 + c] = v + ((c == 0) ? b20 : 0.f);
            }
        }
    }
}

// ---------------- driver -------------------------------------------------------------
template <int CW, bool GEO>
static void run_all(const float* x_dftb, const float* coords, const int* dst,
                    const int* src, const float* W0, const float* b0,
                    const float* Wmp, const float* bmp, const float* W1,
                    const float* b1, const float* W2, const float* b2,
                    float* out, char* ws, hipStream_t stream) {
    constexpr int K = 32 / CW;
    constexpr int EPB = 256 / CW;
    const size_t RES = GEO ? (6u << 20) : (4u << 20);
    size_t sliceB = (size_t)E_EDGES * 9 * CW * sizeof(float);

    float* G = (float*)ws;                                  // 4 KB
    int* row_start = (int*)(ws + (4 << 10));                // 520 KB (131073 ints)
    int* perm      = (int*)(ws + (524 << 10));              // 512 KB
    int* eidx      = (int*)(ws + (1036 << 10));             // 512 KB
    int* cnt       = (int*)(ws + (1548 << 10));             // 512 KB
    int* cursor    = (int*)(ws + (2060 << 10));             // 512 KB
    int* bsum      = (int*)(ws + (2572 << 10));             // 4 KB
    int* blockhist = (int*)(ws + (2576 << 10));             // 64 KB -> end 2640 KB
    float* tbl;
    float4* geo = nullptr;
    if (GEO) {
        tbl = (float*)(ws + (2640 << 10));                  // 768 KB
        geo = (float4*)(ws + (3408 << 10));                 // 2048 KB -> end 5456 < 6144
    } else {
        tbl = (float*)(ws + (1548 << 10));  // overlay cnt+cursor (dead before build_tbl)
    }

    float* reg[K + 1];
    for (int i = 0; i <= K; ++i) reg[i] = (float*)(ws + RES + (size_t)i * sliceB);
    int cur[K];
    for (int i = 0; i < K; ++i) cur[i] = i;
    int spare = K;

    const int EB = E_EDGES / 256;  // 512
    gaunt_init<<<1, 256, 0, stream>>>(G);
    fill_int<<<EB, 256, 0, stream>>>(cnt, E_EDGES, 0);
    csr_count<<<EB, 256, 0, stream>>>(dst, cnt);
    csr_bsum<<<EB, 256, 0, stream>>>(cnt, bsum);
    scan512_wave<<<1, 64, 0, stream>>>(bsum);
    csr_row<<<EB, 256, 0, stream>>>(cnt, bsum, row_start, cursor);
    csr_scatter<<<EB, 256, 0, stream>>>(dst, cursor, eidx);
    sort1<<<EB, 256, 0, stream>>>(cnt, blockhist);
    sort2<<<1, 1024, 0, stream>>>(blockhist);
    sort3<<<EB, 256, 0, stream>>>(cnt, blockhist, perm);
    if (GEO) geo_prep<<<EB, 256, 0, stream>>>(coords, dst, src, eidx, geo);

    P8 Pe;
    for (int i = 0; i < 8; ++i) Pe.p[i] = reg[(i < K) ? cur[i] : 0];
    embed6<CW><<<2048, 256, 0, stream>>>(x_dftb, W0, b0, Pe);

    const int mp_grid = (CW == 8) ? 2048 : 1024;
    for (int step = 0; step < 2; ++step) {
        build_tbl12<<<TBL_N, 256, 0, stream>>>(Wmp + step * 27648, bmp + step * 864, tbl);
        for (int h = 0; h < K; ++h) {
            mp_pull5<CW, GEO><<<mp_grid, 256, 0, stream>>>(
                reg[cur[h]], reg[spare], coords, row_start, eidx, src, perm,
                geo, tbl, G, h);
            int tmp = cur[h]; cur[h] = spare; spare = tmp;
        }
    }
    P8 Pf;
    for (int i = 0; i < 8; ++i) Pf.p[i] = reg[(i < K) ? cur[i] : 0];
    final10<CW><<<2048, 256, 0, stream>>>(Pf, W1, b1, W2, b2, out);
}

extern "C" void kernel_launch(void* const* d_in, const int* in_sizes, int n_in,
                              void* d_out, int out_size, void* d_ws, size_t ws_size,
                              hipStream_t stream) {
    const float* x_dftb = (const float*)d_in[0];
    const float* coords = (const float*)d_in[1];
    const int* dst = (const int*)d_in[2];
    const int* src = (const int*)d_in[3];
    const float* W0 = (const float*)d_in[4];
    const float* b0 = (const float*)d_in[5];
    const float* Wmp = (const float*)d_in[6];
    const float* bmp = (const float*)d_in[7];
    const float* W1 = (const float*)d_in[8];
    const float* b1 = (const float*)d_in[9];
    const float* W2 = (const float*)d_in[10];
    const float* b2 = (const float*)d_in[11];
    float* out = (float*)d_out;
    char* ws = (char*)d_ws;

    size_t s8 = (size_t)E_EDGES * 9 * 8 * sizeof(float);   // 36 MiB
    size_t s4 = (size_t)E_EDGES * 9 * 4 * sizeof(float);   // 18 MiB
    size_t need_geo = (6u << 20) + 5 * s8;                 // ~186 MiB
    size_t need8    = (4u << 20) + 5 * s8;                 // ~184 MiB (known to fit)
    size_t need4    = (4u << 20) + 9 * s4;                 // ~166 MiB
    if (ws_size >= need_geo) {
        run_all<8, true>(x_dftb, coords, dst, src, W0, b0, Wmp, bmp, W1, b1, W2, b2, out, ws, stream);
    } else if (ws_size >= need8) {
        run_all<8, false>(x_dftb, coords, dst, src, W0, b0, Wmp, bmp, W1, b1, W2, b2, out, ws, stream);
    } else if (ws_size >= need4) {
        run_all<4, false>(x_dftb, coords, dst, src, W0, b0, Wmp, bmp, W1, b1, W2, b2, out, ws, stream);
    } else {
        zero_kernel<<<(out_size + 255) / 256, 256, 0, stream>>>(out, (size_t)out_size);
    }
}

// Round 20
// 472.671 us; speedup vs baseline: 1.0179x; 1.0179x over previous
//
#include <hip/hip_runtime.h>

#define E_EDGES 131072
#define FIN 16
#define FF 32

// ---- combo tables: 11 allowed (l1,l2,l3); blocks l=0:[0,1) l=1:[1,4) l=2:[4,9) ----
constexpr int CIDX[11] = {0, 4, 8, 10, 12, 14, 16, 20, 22, 24, 26};
constexpr int CA0[11] = {0, 0, 0, 1, 1, 1, 1, 4, 4, 4, 4};
constexpr int CDA[11] = {1, 1, 1, 3, 3, 3, 3, 5, 5, 5, 5};
constexpr int CQ0[11] = {0, 1, 4, 0, 1, 1, 4, 0, 1, 4, 4};
constexpr int CC0[11] = {0, 1, 4, 1, 0, 4, 1, 4, 1, 0, 4};
constexpr int CDC[11] = {1, 3, 5, 3, 1, 5, 3, 5, 3, 1, 5};
constexpr int CL2[11] = {0, 1, 2, 0, 1, 1, 2, 0, 1, 2, 2};
constexpr int CZ0[11] = {0, 1, 4, 9, 18, 21, 36, 45, 70, 85, 90};    // unpadded cum, 115
constexpr int CZP[11] = {0, 4, 8, 16, 28, 32, 48, 60, 88, 104, 112}; // pad4 offsets, 140

#define TBL_N 512
#define TBL_RMAX 12.0
#define TBL_INVH ((float)(511.0 / 12.0))

struct P8 { float* p[8]; };

// ---------------- Gaunt tensor via exact quadrature (matches reference) -------------
__global__ void gaunt_init(float* __restrict__ G) {
    __shared__ double Ys[128][9];
    __shared__ double wq[128];
    const double ct[8] = {
        -0.9602898564975363, -0.7966664774136267, -0.5255324099163290, -0.1834346424956498,
         0.1834346424956498,  0.5255324099163290,  0.7966664774136267,  0.9602898564975363};
    const double wgt[8] = {
        0.1012285362903763, 0.2223810344533745, 0.3137066458778873, 0.3626837833783620,
        0.3626837833783620, 0.3137066458778873, 0.2223810344533745, 0.1012285362903763};
    const double PI = 3.141592653589793238462643383279502884;
    int t = threadIdx.x;
    if (t < 128) {
        int iq = t >> 4, ip = t & 15;
        double c = ct[iq];
        double s = sqrt(1.0 - c * c);
        double phi = (double)ip * (2.0 * PI / 16.0);
        double x = s * cos(phi), y = s * sin(phi), z = c;
        double* Yp = Ys[t];
        Yp[0] = 0.28209479177387814;
        Yp[1] = 0.4886025119029199 * y;
        Yp[2] = 0.4886025119029199 * z;
        Yp[3] = 0.4886025119029199 * x;
        Yp[4] = 1.0925484305920792 * x * y;
        Yp[5] = 1.0925484305920792 * y * z;
        Yp[6] = 0.31539156525252005 * (3.0 * z * z - 1.0);
        Yp[7] = 1.0925484305920792 * x * z;
        Yp[8] = 0.5462742152960396 * (x * x - y * y);
        wq[t] = wgt[iq] * (2.0 * PI / 16.0);
    }
    __syncthreads();
    for (int idx = t; idx < 729; idx += blockDim.x) {
        int a = idx / 81, b = (idx / 9) % 9, cc = idx % 9;
        double sum = 0.0;
        for (int q = 0; q < 128; ++q) sum += wq[q] * Ys[q][a] * Ys[q][b] * Ys[q][cc];
        G[idx] = (float)sum;
    }
}

// ---------------- small utility kernels ---------------------------------------------
__global__ __launch_bounds__(256) void zero_kernel(float* __restrict__ p, size_t n) {
    size_t i = (size_t)blockIdx.x * 256 + threadIdx.x;
    if (i < n) p[i] = 0.f;
}
__global__ __launch_bounds__(256) void fill_int(int* __restrict__ p, int n, int v) {
    int i = blockIdx.x * 256 + threadIdx.x;
    if (i < n) p[i] = v;
}

// ---------------- CSR build ----------------------------------------------------------
__global__ __launch_bounds__(256) void csr_count(const int* __restrict__ dst,
                                                 int* __restrict__ cnt) {
    int e = blockIdx.x * 256 + threadIdx.x;
    atomicAdd(&cnt[dst[e]], 1);  // 131072 spread addresses: low contention
}
__global__ __launch_bounds__(256) void csr_bsum(const int* __restrict__ cnt,
                                                int* __restrict__ bsum) {
    int i = blockIdx.x * 256 + threadIdx.x;
    int v = cnt[i];
#pragma unroll
    for (int off = 32; off; off >>= 1) v += __shfl_down(v, off, 64);
    __shared__ int w4[4];
    if ((threadIdx.x & 63) == 0) w4[threadIdx.x >> 6] = v;
    __syncthreads();
    if (threadIdx.x == 0) bsum[blockIdx.x] = w4[0] + w4[1] + w4[2] + w4[3];
}
__global__ void scan512_wave(int* __restrict__ b) {
    int lane = threadIdx.x;  // 64 threads
    int run = 0;
    for (int c = 0; c < 8; ++c) {
        int v = b[c * 64 + lane];
        int s = v;
#pragma unroll
        for (int off = 1; off < 64; off <<= 1) {
            int t = __shfl_up(s, off, 64);
            if (lane >= off) s += t;
        }
        b[c * 64 + lane] = run + s - v;
        run += __shfl(s, 63, 64);
    }
}
__global__ __launch_bounds__(256) void csr_row(const int* __restrict__ cnt,
                                               const int* __restrict__ bsum,
                                               int* __restrict__ row_start,
                                               int* __restrict__ cursor) {
    __shared__ int sd[256];
    const int i = blockIdx.x * 256 + threadIdx.x;
    const int my = cnt[i];
    sd[threadIdx.x] = my;
    __syncthreads();
    for (int off = 1; off < 256; off <<= 1) {
        int t = (threadIdx.x >= off) ? sd[threadIdx.x - off] : 0;
        __syncthreads();
        sd[threadIdx.x] += t;
        __syncthreads();
    }
    int rs = bsum[blockIdx.x] + sd[threadIdx.x] - my;
    row_start[i] = rs;
    cursor[i] = rs;
    if (blockIdx.x == 511 && threadIdx.x == 255)
        row_start[E_EDGES] = bsum[511] + sd[255];
}
__global__ __launch_bounds__(256) void csr_scatter(const int* __restrict__ dst,
                                                   int* __restrict__ cursor,
                                                   int* __restrict__ eidx) {
    int e = blockIdx.x * 256 + threadIdx.x;
    int pos = atomicAdd(&cursor[dst[e]], 1);  // spread addresses: fine
    eidx[pos] = e;
}

// ---------------- degree counting-sort, DESCENDING degree (LPT schedule) ------------
__global__ __launch_bounds__(256) void sort1(const int* __restrict__ cnt,
                                             int* __restrict__ blockhist) {
    __shared__ int h[32];
    if (threadIdx.x < 32) h[threadIdx.x] = 0;
    __syncthreads();
    int n = blockIdx.x * 256 + threadIdx.x;
    int d = cnt[n]; if (d > 31) d = 31;
    atomicAdd(&h[31 - d], 1);  // bin flip: heavy nodes first
    __syncthreads();
    if (threadIdx.x < 32) blockhist[threadIdx.x * 512 + blockIdx.x] = h[threadIdx.x];
}
__global__ __launch_bounds__(1024) void sort2(int* __restrict__ blockhist) {
    __shared__ int tot[32];
    int wv = threadIdx.x >> 6, lane = threadIdx.x & 63;  // 16 waves, 2 bins each
#pragma unroll
    for (int bi = 0; bi < 2; ++bi) {
        int bin = wv * 2 + bi;
        int run = 0;
        for (int c = 0; c < 8; ++c) {
            int v = blockhist[bin * 512 + c * 64 + lane];
            int s = v;
#pragma unroll
            for (int off = 1; off < 64; off <<= 1) {
                int t = __shfl_up(s, off, 64);
                if (lane >= off) s += t;
            }
            blockhist[bin * 512 + c * 64 + lane] = run + s - v;
            run += __shfl(s, 63, 64);
        }
        if (lane == 0) tot[bin] = run;
    }
    __syncthreads();
    if (threadIdx.x == 0) {
        int run = 0;
        for (int i = 0; i < 32; ++i) { int t = tot[i]; tot[i] = run; run += t; }
    }
    __syncthreads();
#pragma unroll
    for (int bi = 0; bi < 2; ++bi) {
        int bin = wv * 2 + bi;
        int base = tot[bin];
        for (int c = 0; c < 8; ++c) blockhist[bin * 512 + c * 64 + lane] += base;
    }
}
__global__ __launch_bounds__(256) void sort3(const int* __restrict__ cnt,
                                             const int* __restrict__ blockhist,
                                             int* __restrict__ perm) {
    __shared__ int cur[32];
    if (threadIdx.x < 32) cur[threadIdx.x] = blockhist[threadIdx.x * 512 + blockIdx.x];
    __syncthreads();
    int n = blockIdx.x * 256 + threadIdx.x;
    int d = cnt[n]; if (d > 31) d = 31;
    int pos = atomicAdd(&cur[31 - d], 1);  // bin flip (must match sort1)
    perm[pos] = n;
}

// ---------------- geometry packet, CSR order: {rx, ry, rz, bits(src)} ---------------
__global__ __launch_bounds__(256) void geo_prep(const float* __restrict__ coords,
                                                const int* __restrict__ dst,
                                                const int* __restrict__ src,
                                                const int* __restrict__ eidx,
                                                float4* __restrict__ geo) {
    int p = blockIdx.x * 256 + threadIdx.x;
    int e = eidx[p];
    int s = src[e], d = dst[e];
    float4 g;
    g.x = coords[3 * d + 0] - coords[3 * s + 0];
    g.y = coords[3 * d + 1] - coords[3 * s + 1];
    g.z = coords[3 * d + 2] - coords[3 * s + 2];
    g.w = __int_as_float(s);
    geo[p] = g;
}

// ---------------- coef lookup table, layout [u][f][12] (k padded 11->12) ------------
__global__ __launch_bounds__(256) void build_tbl12(const float* __restrict__ Wm,
                                                   const float* __restrict__ bm,
                                                   float* __restrict__ tbl) {
    __shared__ float rad[32];
    const int u = blockIdx.x;
    const int tid = threadIdx.x;
    if (tid < 32) {
        double r = (double)u * (TBL_RMAX / (double)(TBL_N - 1));
        double c = (double)tid * (4.0 / 31.0);
        double d = r - c;
        rad[tid] = (float)exp(-d * d);
    }
    __syncthreads();
    for (int i = tid; i < 352; i += 256) {
        int k = i >> 5, f = i & 31;
        float acc = bm[CIDX[k] * 32 + f];
        const float* W = Wm + CIDX[k] * 1024 + f;
#pragma unroll
        for (int b = 0; b < 32; ++b) acc = fmaf(rad[b], W[b * 32], acc);
        tbl[(size_t)u * 384 + f * 12 + k] = acc;
    }
}

// ---------------- embed6: coop LDS stage of x + W0 in regs + float4 out -------------
template <int CW>
__global__ __launch_bounds__(256) void embed6(
    const float* __restrict__ xin, const float* __restrict__ W0,
    const float* __restrict__ b0, P8 P) {
    constexpr int K = 32 / CW;
    __shared__ float4 Xin4[288];   // 8 edges x 36 float4 (4608 B), coalesced-staged
    __shared__ float Xs[8][9][36];
    const int tid = threadIdx.x;
    const int g = tid >> 5, f = tid & 31;
    float w0r[3][16];
#pragma unroll
    for (int l = 0; l < 3; ++l)
#pragma unroll
        for (int gi = 0; gi < 16; ++gi) w0r[l][gi] = W0[(l * FIN + gi) * FF + f];
    const float b0f = b0[f];

    constexpr int NG = E_EDGES / 8;  // 16384 edge-groups
    for (int nb = blockIdx.x; nb < NG; nb += gridDim.x) {
        const size_t e0 = (size_t)nb * 8;
        const float4* src4 = (const float4*)(xin + e0 * 144);
        for (int i = tid; i < 288; i += 256) Xin4[i] = src4[i];
        __syncthreads();  // bar A (also protects prior iter's Xs copy-out reads)
#pragma unroll
        for (int c = 0; c < 9; ++c) {
            const int l = (c == 0) ? 0 : ((c < 4) ? 1 : 2);
            float acc = (c == 0) ? b0f : 0.f;
#pragma unroll
            for (int q = 0; q < 4; ++q) {
                float4 xv = Xin4[g * 36 + c * 4 + q];
                acc = fmaf(xv.x, w0r[l][q * 4 + 0], acc);
                acc = fmaf(xv.y, w0r[l][q * 4 + 1], acc);
                acc = fmaf(xv.z, w0r[l][q * 4 + 2], acc);
                acc = fmaf(xv.w, w0r[l][q * 4 + 3], acc);
            }
            Xs[g][c][f] = acc;
        }
        __syncthreads();  // bar B
        constexpr int QW = CW / 4;
        constexpr int RSZ4 = 8 * 9 * QW;
#pragma unroll
        for (int h = 0; h < K; ++h) {
            float4* dstp = (float4*)(P.p[h] + e0 * 9 * CW);
            for (int i = tid; i < RSZ4; i += 256) {
                int fq = i % QW;
                int rc = i / QW;
                float4 v = *(const float4*)&Xs[rc / 9][rc % 9][h * CW + fq * 4];
                dstp[i] = v;
            }
        }
    }
}

// ---------------- per-combo einsum piece (all compile-time indexed) -----------------
template <int K>
__device__ __forceinline__ void comboP(const float* __restrict__ zrow,
                                       const float (&coef)[11], const float (&xa)[9],
                                       float (&acc)[9]) {
    constexpr int A0 = CA0[K], DA = CDA[K], C0 = CC0[K], DC = CDC[K];
    constexpr int SZ = DA * DC, N4 = (SZ + 3) / 4, ZP = CZP[K];
    float zz[N4 * 4];
    const float4* zp = (const float4*)(zrow + ZP);
#pragma unroll
    for (int j = 0; j < N4; ++j) {
        float4 v = zp[j];
        zz[4 * j + 0] = v.x; zz[4 * j + 1] = v.y; zz[4 * j + 2] = v.z; zz[4 * j + 3] = v.w;
    }
    float m[DC] = {};
#pragma unroll
    for (int a = 0; a < DA; ++a)
#pragma unroll
        for (int c = 0; c < DC; ++c) m[c] = fmaf(xa[A0 + a], zz[a * DC + c], m[c]);
#pragma unroll
    for (int c = 0; c < DC; ++c) acc[C0 + c] = fmaf(coef[K], m[c], acc[C0 + c]);
}

// ---------------- message pass, CSR pull, chunk h, CUBIC tbl, utab in regs ----------
template <int CW, bool GEO>
__global__ __launch_bounds__(256) void mp_pull5(
    const float* __restrict__ Xold, float* __restrict__ Xnew,
    const float* __restrict__ coords,
    const int* __restrict__ row_start, const int* __restrict__ eidx,
    const int* __restrict__ src, const int* __restrict__ perm,
    const float4* __restrict__ geo,
    const float* __restrict__ tbl, const float* __restrict__ Gglob, int h) {
    constexpr int EPB = 256 / CW;
    constexpr int NB_TOT = E_EDGES / EPB;
    constexpr int NJ = (115 + CW - 1) / CW;  // z entries per lane
    __shared__ float gG[729];
    __shared__ float z_s[EPB * 140];
    const int tid = threadIdx.x;
    for (int i = tid; i < 729; i += 256) gG[i] = Gglob[i];
    __syncthreads();

    const int g = tid / CW, fc = tid % CW;
    const int f = h * CW + fc;
    float* zrow = &z_s[g * 140];

    // per-lane z-table entries (STATIC index -> registers, computed once)
    int utab[NJ];
#pragma unroll
    for (int j = 0; j < NJ; ++j) {
        int t = fc + j * CW;
        int enc = 0;
        if (t < 115) {
            int k = 0;
#pragma unroll
            for (int kk = 1; kk < 11; ++kk) if (t >= CZ0[kk]) k = kk;
            int loc = t - CZ0[k];
            int dc = CDC[k];
            int a = loc / dc, c = loc - a * dc;
            int base = (CA0[k] + a) * 81 + CQ0[k] * 9 + (CC0[k] + c);
            enc = ((CZP[k] + loc) << 12) | (CL2[k] << 10) | base;
        }
        utab[j] = enc;
    }

    for (int nb = blockIdx.x; nb < NB_TOT; nb += gridDim.x) {
        const int d = perm[nb * EPB + g];
        const int r0 = row_start[d], r1 = row_start[d + 1];
        float acc[9];
#pragma unroll
        for (int a = 0; a < 9; ++a) acc[a] = Xold[((size_t)d * 9 + a) * CW + fc];
        float ddx = 0.f, ddy = 0.f, ddz = 0.f;
        if (!GEO) { ddx = coords[3 * d]; ddy = coords[3 * d + 1]; ddz = coords[3 * d + 2]; }

        // 1-deep software pipeline over the row's edges
        float prx = 0.f, pry = 0.f, prz = 0.f;
        int ps = 0;
        float pxa[9];
        if (r0 < r1) {
            if (GEO) {
                float4 gv = geo[r0];
                prx = gv.x; pry = gv.y; prz = gv.z; ps = __float_as_int(gv.w);
            } else {
                int pe = eidx[r0]; ps = src[pe];
                prx = ddx - coords[3 * ps]; pry = ddy - coords[3 * ps + 1];
                prz = ddz - coords[3 * ps + 2];
            }
#pragma unroll
            for (int a = 0; a < 9; ++a) pxa[a] = Xold[((size_t)ps * 9 + a) * CW + fc];
        }
        for (int p = r0; p < r1; ++p) {
            const float rx = prx, ry = pry, rz = prz;
            float xa[9];
#pragma unroll
            for (int a = 0; a < 9; ++a) xa[a] = pxa[a];
            if (p + 1 < r1) {  // prefetch next edge under this edge's compute
                if (GEO) {
                    float4 gv = geo[p + 1];
                    prx = gv.x; pry = gv.y; prz = gv.z; ps = __float_as_int(gv.w);
                } else {
                    int pe = eidx[p + 1]; ps = src[pe];
                    prx = ddx - coords[3 * ps]; pry = ddy - coords[3 * ps + 1];
                    prz = ddz - coords[3 * ps + 2];
                }
#pragma unroll
                for (int a = 0; a < 9; ++a) pxa[a] = Xold[((size_t)ps * 9 + a) * CW + fc];
            }
            float r = sqrtf(rx * rx + ry * ry + rz * rz + 1e-8f);
            float inv = 1.f / r;
            float ux = rx * inv, uy = ry * inv, uz = rz * inv;
            float y9[9];
            y9[0] = 0.28209479177387814f;
            y9[1] = 0.4886025119029199f * uy; y9[2] = 0.4886025119029199f * uz;
            y9[3] = 0.4886025119029199f * ux;
            y9[4] = 1.0925484305920792f * ux * uy; y9[5] = 1.0925484305920792f * uy * uz;
            y9[6] = 0.31539156525252005f * (3.f * uz * uz - 1.f);
            y9[7] = 1.0925484305920792f * ux * uz;
            y9[8] = 0.5462742152960396f * (ux * ux - uy * uy);
            // coef via CUBIC Lagrange interp; tbl layout [u][f][12]
            float rt = r * TBL_INVH;
            int u = (int)rt;
            u = (u < 1) ? 1 : ((u > TBL_N - 3) ? (TBL_N - 3) : u);
            float w = rt - (float)u;
            float wp1 = w + 1.f, wm1 = w - 1.f, wm2 = w - 2.f;
            float lm = -w * wm1 * wm2 * (1.f / 6.f);
            float l0 = wp1 * wm1 * wm2 * 0.5f;
            float l1 = -wp1 * w * wm2 * 0.5f;
            float l2 = wp1 * w * wm1 * (1.f / 6.f);
            const float* tbp = tbl + (size_t)(u - 1) * 384 + f * 12;
            float coef[11];
            {
                float4 a0 = *(const float4*)(tbp);
                float4 a1 = *(const float4*)(tbp + 4);
                float4 a2 = *(const float4*)(tbp + 8);
                float tk[12] = {a0.x, a0.y, a0.z, a0.w, a1.x, a1.y, a1.z, a1.w,
                                a2.x, a2.y, a2.z, a2.w};
#pragma unroll
                for (int k = 0; k < 11; ++k) coef[k] = lm * tk[k];
            }
#pragma unroll
            for (int tap = 0; tap < 3; ++tap) {
                const float lw = (tap == 0) ? l0 : ((tap == 1) ? l1 : l2);
                const float* tq = tbp + (tap + 1) * 384;
                float4 a0 = *(const float4*)(tq);
                float4 a1 = *(const float4*)(tq + 4);
                float4 a2 = *(const float4*)(tq + 8);
                float tk[12] = {a0.x, a0.y, a0.z, a0.w, a1.x, a1.y, a1.z, a1.w,
                                a2.x, a2.y, a2.z, a2.w};
#pragma unroll
                for (int k = 0; k < 11; ++k) coef[k] = fmaf(lw, tk[k], coef[k]);
            }
            // z[t] = sum_b Y[Q0+b] * G[base + 9b]; utab from registers, gG broadcast
#pragma unroll
            for (int j = 0; j < NJ; ++j) {
                int t = fc + j * CW;
                if (t < 115) {
                    int u2 = utab[j];
                    int base = u2 & 0x3FF;
                    int l2u = (u2 >> 10) & 3;
                    float zv;
                    if (l2u == 0) {
                        zv = y9[0] * gG[base];
                    } else if (l2u == 1) {
                        zv = y9[1] * gG[base];
                        zv = fmaf(y9[2], gG[base + 9], zv);
                        zv = fmaf(y9[3], gG[base + 18], zv);
                    } else {
                        zv = y9[4] * gG[base];
                        zv = fmaf(y9[5], gG[base + 9], zv);
                        zv = fmaf(y9[6], gG[base + 18], zv);
                        zv = fmaf(y9[7], gG[base + 27], zv);
                        zv = fmaf(y9[8], gG[base + 36], zv);
                    }
                    zrow[u2 >> 12] = zv;
                }
            }
            asm volatile("s_waitcnt lgkmcnt(0)" ::: "memory");
            comboP<0>(zrow, coef, xa, acc);
            comboP<1>(zrow, coef, xa, acc);
            comboP<2>(zrow, coef, xa, acc);
            comboP<3>(zrow, coef, xa, acc);
            comboP<4>(zrow, coef, xa, acc);
            comboP<5>(zrow, coef, xa, acc);
            comboP<6>(zrow, coef, xa, acc);
            comboP<7>(zrow, coef, xa, acc);
            comboP<8>(zrow, coef, xa, acc);
            comboP<9>(zrow, coef, xa, acc);
            comboP<10>(zrow, coef, xa, acc);
        }
#pragma unroll
        for (int a = 0; a < 9; ++a) Xnew[((size_t)d * 9 + a) * CW + fc] = acc[a];
    }
}

// ---------------- DPP helpers --------------------------------------------------------
template <int CTRL>
__device__ __forceinline__ float dpp_add(float v) {
    int t = __builtin_amdgcn_update_dpp(0, __builtin_bit_cast(int, v),
                                        CTRL, 0xF, 0xF, true);
    return v + __builtin_bit_cast(float, t);
}
__device__ __forceinline__ float red8(float v) {
    v = dpp_add<0x111>(v);  // row_shr:1
    v = dpp_add<0x112>(v);  // row_shr:2
    v = dpp_add<0x114>(v);  // row_shr:4
    return v;               // valid in lane 7 of each 8-lane group
}

// ---------------- final9: 8 edges x 8 f-quads; unroll-1 loops + sched fences --------
template <int CW>
__global__ __launch_bounds__(256) void final9(
    P8 P, const float* __restrict__ W1, const float* __restrict__ b1,
    const float* __restrict__ W2, const float* __restrict__ b2,
    float* __restrict__ out) {
    constexpr int K = 32 / CW;
    constexpr int QPR = CW / 4;  // f-quads per region
    __shared__ float W_s[3 * 32 * 32];  // 12 KB, same layout as W1
    const int tid = threadIdx.x;
    for (int i = tid; i < 3072; i += 256) W_s[i] = W1[i];
    __syncthreads();

    const int lane = tid & 63;
    const int e_sub = lane >> 3;   // 8 edges per wave
    const int fq = lane & 7;       // 8 f-quads, this lane owns f = fq*4 .. fq*4+3
    float w2r[3][4];
#pragma unroll
    for (int l = 0; l < 3; ++l)
#pragma unroll
        for (int j = 0; j < 4; ++j) w2r[l][j] = W2[l * 32 + fq * 4 + j];
    float b1r[4];
#pragma unroll
    for (int j = 0; j < 4; ++j) b1r[j] = b1[fq * 4 + j];
    const float b20 = b2[0];

    const int wv = (blockIdx.x * 256 + tid) >> 6;
    const int nw = (gridDim.x * 256) >> 6;
    constexpr int NG = E_EDGES / 8;

    for (int gp = wv; gp < NG; gp += nw) {
        const size_t e = (size_t)gp * 8 + e_sub;
        float t[9][4];
#pragma unroll
        for (int j = 0; j < 4; ++j) t[0][j] = b1r[j];
#pragma unroll
        for (int c = 1; c < 9; ++c)
#pragma unroll
            for (int j = 0; j < 4; ++j) t[c][j] = 0.f;

#pragma unroll 1
        for (int h = 0; h < K; ++h) {          // region loop: NOT unrolled
            const float* xbase = P.p[0];
#pragma unroll
            for (int i = 1; i < K; ++i) xbase = (h == i) ? P.p[i] : xbase;
            xbase += (e * 9) * CW;
#pragma unroll 1
            for (int q2 = 0; q2 < QPR; ++q2) { // quad-in-region loop: NOT unrolled
                const int gq = h * QPR + q2;
                const float* xb = xbase + q2 * 4;
                float wq[4][4];  // W quad for ONE l-class at a time
                // ---- l = 0 : c = 0 ----
#pragma unroll
                for (int gi = 0; gi < 4; ++gi) {
                    float4 wv4 = *(const float4*)&W_s[(0 * 32 + gq * 4 + gi) * 32 + fq * 4];
                    wq[gi][0] = wv4.x; wq[gi][1] = wv4.y; wq[gi][2] = wv4.z; wq[gi][3] = wv4.w;
                }
                {
                    float4 xv = *(const float4*)&xb[0 * CW];
                    float xr[4] = {xv.x, xv.y, xv.z, xv.w};
#pragma unroll
                    for (int gi = 0; gi < 4; ++gi)
#pragma unroll
                        for (int j = 0; j < 4; ++j) t[0][j] = fmaf(xr[gi], wq[gi][j], t[0][j]);
                }
                __builtin_amdgcn_sched_barrier(0);
                // ---- l = 1 : c = 1..3 ----
#pragma unroll
                for (int gi = 0; gi < 4; ++gi) {
                    float4 wv4 = *(const float4*)&W_s[(1 * 32 + gq * 4 + gi) * 32 + fq * 4];
                    wq[gi][0] = wv4.x; wq[gi][1] = wv4.y; wq[gi][2] = wv4.z; wq[gi][3] = wv4.w;
                }
#pragma unroll
                for (int c = 1; c < 4; ++c) {
                    float4 xv = *(const float4*)&xb[c * CW];
                    float xr[4] = {xv.x, xv.y, xv.z, xv.w};
#pragma unroll
                    for (int gi = 0; gi < 4; ++gi)
#pragma unroll
                        for (int j = 0; j < 4; ++j) t[c][j] = fmaf(xr[gi], wq[gi][j], t[c][j]);
                }
                __builtin_amdgcn_sched_barrier(0);
                // ---- l = 2 : c = 4..8 ----
#pragma unroll
                for (int gi = 0; gi < 4; ++gi) {
                    float4 wv4 = *(const float4*)&W_s[(2 * 32 + gq * 4 + gi) * 32 + fq * 4];
                    wq[gi][0] = wv4.x; wq[gi][1] = wv4.y; wq[gi][2] = wv4.z; wq[gi][3] = wv4.w;
                }
#pragma unroll
                for (int c = 4; c < 9; ++c) {
                    float4 xv = *(const float4*)&xb[c * CW];
                    float xr[4] = {xv.x, xv.y, xv.z, xv.w};
#pragma unroll
                    for (int gi = 0; gi < 4; ++gi)
#pragma unroll
                        for (int j = 0; j < 4; ++j) t[c][j] = fmaf(xr[gi], wq[gi][j], t[c][j]);
                }
                __builtin_amdgcn_sched_barrier(0);
            }
        }
        float gw[3][4];
#pragma unroll
        for (int j = 0; j < 4; ++j) {
            const float gate = (t[0][j] > 0.f) ? 1.f : 0.f;
#pragma unroll
            for (int l = 0; l < 3; ++l) gw[l][j] = gate * w2r[l][j];
        }
#pragma unroll
        for (int c = 0; c < 9; ++c) {
            const int l = (c == 0) ? 0 : ((c < 4) ? 1 : 2);
            float v = t[c][0] * gw[l][0];
            v = fmaf(t[c][1], gw[l][1], v);
            v = fmaf(t[c][2], gw[l][2], v);
            v = fmaf(t[c][3], gw[l][3], v);
            v = red8(v);
            if (fq == 7) out[e * 9 + c] = v + ((c == 0) ? b20 : 0.f);
        }
    }
}

// ---------------- driver -------------------------------------------------------------
template <int CW, bool GEO>
static void run_all(const float* x_dftb, const float* coords, const int* dst,
                    const int* src, const float* W0, const float* b0,
                    const float* Wmp, const float* bmp, const float* W1,
                    const float* b1, const float* W2, const float* b2,
                    float* out, char* ws, hipStream_t stream) {
    constexpr int K = 32 / CW;
    constexpr int EPB = 256 / CW;
    const size_t RES = GEO ? (6u << 20) : (4u << 20);
    size_t sliceB = (size_t)E_EDGES * 9 * CW * sizeof(float);

    float* G = (float*)ws;                                  // 4 KB
    int* row_start = (int*)(ws + (4 << 10));                // 520 KB (131073 ints)
    int* perm      = (int*)(ws + (524 << 10));              // 512 KB
    int* eidx      = (int*)(ws + (1036 << 10));             // 512 KB
    int* cnt       = (int*)(ws + (1548 << 10));             // 512 KB
    int* cursor    = (int*)(ws + (2060 << 10));             // 512 KB
    int* bsum      = (int*)(ws + (2572 << 10));             // 4 KB
    int* blockhist = (int*)(ws + (2576 << 10));             // 64 KB -> end 2640 KB
    float* tbl;
    float4* geo = nullptr;
    if (GEO) {
        tbl = (float*)(ws + (2640 << 10));                  // 768 KB
        geo = (float4*)(ws + (3408 << 10));                 // 2048 KB -> end 5456 < 6144
    } else {
        tbl = (float*)(ws + (1548 << 10));  // overlay cnt+cursor (dead before build_tbl)
    }

    float* reg[K + 1];
    for (int i = 0; i <= K; ++i) reg[i] = (float*)(ws + RES + (size_t)i * sliceB);
    int cur[K];
    for (int i = 0; i < K; ++i) cur[i] = i;
    int spare = K;

    const int EB = E_EDGES / 256;  // 512
    gaunt_init<<<1, 256, 0, stream>>>(G);
    fill_int<<<EB, 256, 0, stream>>>(cnt, E_EDGES, 0);
    csr_count<<<EB, 256, 0, stream>>>(dst, cnt);
    csr_bsum<<<EB, 256, 0, stream>>>(cnt, bsum);
    scan512_wave<<<1, 64, 0, stream>>>(bsum);
    csr_row<<<EB, 256, 0, stream>>>(cnt, bsum, row_start, cursor);
    csr_scatter<<<EB, 256, 0, stream>>>(dst, cursor, eidx);
    sort1<<<EB, 256, 0, stream>>>(cnt, blockhist);
    sort2<<<1, 1024, 0, stream>>>(blockhist);
    sort3<<<EB, 256, 0, stream>>>(cnt, blockhist, perm);
    if (GEO) geo_prep<<<EB, 256, 0, stream>>>(coords, dst, src, eidx, geo);

    P8 Pe;
    for (int i = 0; i < 8; ++i) Pe.p[i] = reg[(i < K) ? cur[i] : 0];
    embed6<CW><<<2048, 256, 0, stream>>>(x_dftb, W0, b0, Pe);

    const int mp_grid = (CW == 8) ? 2048 : 1024;
    for (int step = 0; step < 2; ++step) {
        build_tbl12<<<TBL_N, 256, 0, stream>>>(Wmp + step * 27648, bmp + step * 864, tbl);
        for (int h = 0; h < K; ++h) {
            mp_pull5<CW, GEO><<<mp_grid, 256, 0, stream>>>(
                reg[cur[h]], reg[spare], coords, row_start, eidx, src, perm,
                geo, tbl, G, h);
            int tmp = cur[h]; cur[h] = spare; spare = tmp;
        }
    }
    P8 Pf;
    for (int i = 0; i < 8; ++i) Pf.p[i] = reg[(i < K) ? cur[i] : 0];
    final9<CW><<<2048, 256, 0, stream>>>(Pf, W1, b1, W2, b2, out);
}

extern "C" void kernel_launch(void* const* d_in, const int* in_sizes, int n_in,
                              void* d_out, int out_size, void* d_ws, size_t ws_size,
                              hipStream_t stream) {
    const float* x_dftb = (const float*)d_in[0];
    const float* coords = (const float*)d_in[1];
    const int* dst = (const int*)d_in[2];
    const int* src = (const int*)d_in[3];
    const float* W0 = (const float*)d_in[4];
    const float* b0 = (const float*)d_in[5];
    const float* Wmp = (const float*)d_in[6];
    const float* bmp = (const float*)d_in[7];
    const float* W1 = (const float*)d_in[8];
    const float* b1 = (const float*)d_in[9];
    const float* W2 = (const float*)d_in[10];
    const float* b2 = (const float*)d_in[11];
    float* out = (float*)d_out;
    char* ws = (char*)d_ws;

    size_t s8 = (size_t)E_EDGES * 9 * 8 * sizeof(float);   // 36 MiB
    size_t s4 = (size_t)E_EDGES * 9 * 4 * sizeof(float);   // 18 MiB
    size_t need_geo = (6u << 20) + 5 * s8;                 // ~186 MiB
    size_t need8    = (4u << 20) + 5 * s8;                 // ~184 MiB (known to fit)
    size_t need4    = (4u << 20) + 9 * s4;                 // ~166 MiB
    if (ws_size >= need_geo) {
        run_all<8, true>(x_dftb, coords, dst, src, W0, b0, Wmp, bmp, W1, b1, W2, b2, out, ws, stream);
    } else if (ws_size >= need8) {
        run_all<8, false>(x_dftb, coords, dst, src, W0, b0, Wmp, bmp, W1, b1, W2, b2, out, ws, stream);
    } else if (ws_size >= need4) {
        run_all<4, false>(x_dftb, coords, dst, src, W0, b0, Wmp, bmp, W1, b1, W2, b2, out, ws, stream);
    } else {
        zero_kernel<<<(out_size + 255) / 256, 256, 0, stream>>>(out, (size_t)out_size);
    }
}